// Round 10
// baseline (481.293 us; speedup 1.0000x reference)
//
#include <hip/hip_runtime.h>
#include <hip/hip_bf16.h>
#include <cstdint>
#include <cstddef>

#define EPS 1e-5f
#define BB 4096
#define TT 64
#define NBLK 2
#define MROWS (BB * TT)

typedef unsigned short ushort_t;
typedef __attribute__((ext_vector_type(8))) short short8;
typedef __attribute__((ext_vector_type(4))) float floatx4;

__device__ __forceinline__ ushort_t f2b(float f) {
    __hip_bfloat16 h = __float2bfloat16(f);
    return *reinterpret_cast<ushort_t*>(&h);
}
__device__ __forceinline__ float tanh_fast(float z) {
    return 1.f - 2.f / (__expf(2.f * z) + 1.f);
}
// LDS-only barrier, single asm statement (round-5 lesson: separate
// builtin_amdgcn_s_barrier is IntrNoMem and lets LDS ops hoist past the
// waitcnt). Omits vmcnt drain: global buffers are wg-exclusive.
__device__ __forceinline__ void lds_barrier() {
    asm volatile("s_waitcnt lgkmcnt(0)\n\ts_barrier" ::: "memory");
}

// ---------------- all weight converts in one launch ----------------
__global__ __launch_bounds__(256) void k_cvtall(
    const float* __restrict__ Wg, const float* __restrict__ W1,
    const float* __restrict__ W2, ushort_t* __restrict__ Wgt,
    ushort_t* __restrict__ W1t, ushort_t* __restrict__ W2t) {
    int idx = blockIdx.x * 256 + threadIdx.x;
    if (idx < 2 * 512 * 128) {
        int blk = idx >> 16, r = idx & 65535;
        int n = r >> 7, k = r & 127;
        Wgt[idx] = f2b(Wg[(size_t)blk * 65536 + k * 512 + n]);
    } else if (idx < 2 * 512 * 128 + 2 * 128 * 128) {
        int i2 = idx - 2 * 512 * 128;
        int blk = i2 >> 14, r = i2 & 16383;
        int n = r >> 7, k = r & 127;
        W1t[i2] = f2b(W1[(size_t)blk * 16384 + k * 128 + n]);
    } else {
        int i2 = idx - (2 * 512 * 128 + 2 * 128 * 128);
        int blk = i2 >> 14, r = i2 & 16383;
        int n = r >> 7, k = r & 127;
        W2t[i2] = f2b(W2[(size_t)blk * 16384 + k * 128 + n]);
    }
}

// ---------------- fused [embed +] gate-GEMM + sLSTM scan + GroupNorm + residual --------
// grid = BB/16 = 256 wgs (1 wg/CU — the race-free family; multi-wg scan raced in
// rounds 5/8), 1024 thr = 16 waves = 4 waves/SIMD (up from 2: halves per-wave
// phase work, doubles schedulable streams per barrier window).
// Phase B: wave = (gate, quarter): gate = wave>>2, cols quarter*32..+32 of gate.
//   WB[4][2], RB[2] (head = quarter). 10 MFMAs/wave, M=16 rows all live.
// Phase A/C: wave bo = batch; lane dv owns dims dv*2..dv*2+1 (LN = intra-wave shfl).
// LASTONLY: blk-1 scan's h rows are dead except t=TT-1 (store-skip only).
template <bool EMBED, bool LASTONLY>
__global__ __launch_bounds__(1024) void k_gslstm(
    float* __restrict__ h, const float* __restrict__ x,
    const float* __restrict__ w_in, const float* __restrict__ b_in,
    const ushort_t* __restrict__ Wgt, const float* __restrict__ bg,
    const float* __restrict__ Rg,
    const float* __restrict__ ln1g, const float* __restrict__ ln1b,
    const float* __restrict__ gng, const float* __restrict__ gnb) {
    __shared__ ushort_t Afrag[16][136];  // LN1(h_in) bf16, [m][k]
    __shared__ ushort_t Hlds[16][136];   // h_prev bf16, [m][k]
    __shared__ float Xbuf[16][516];      // gate preacts fp32, [b][g*128+d]

    int tid = threadIdx.x;        // 0..1023
    int lane = tid & 63;
    int wave = tid >> 6;          // 0..15
    int gate = wave >> 2;         // phase B
    int quarter = wave & 3;
    int q = lane >> 4, ml = lane & 15;
    int bo = wave;                // phase A/C: one wave per batch
    int dv = lane;                // dims dv*2 .. dv*2+1
    int b0 = blockIdx.x * 16;

    // ---- static setup ----
    short8 WB[4][2];  // [k-slice][n-slice] of this wave's 32 columns
#pragma unroll
    for (int ks = 0; ks < 4; ++ks)
#pragma unroll
        for (int s = 0; s < 2; ++s)
            WB[ks][s] = *(const short8*)(Wgt +
                ((size_t)(gate * 128 + quarter * 32 + s * 16 + ml) * 128 + ks * 32 + q * 8));
    float biasv[2];
#pragma unroll
    for (int s = 0; s < 2; ++s) biasv[s] = bg[gate * 128 + quarter * 32 + s * 16 + ml];
    // R for head hh = quarter (this wave's 32 cols == that head's dims)
    short8 RB[2];
#pragma unroll
    for (int sr = 0; sr < 2; ++sr) {
        ushort_t tmp[8];
#pragma unroll
        for (int jj = 0; jj < 8; ++jj)
            tmp[jj] = f2b(Rg[((size_t)(gate * 4 + quarter) * 32 + q * 8 + jj) * 32 +
                           sr * 16 + ml]);
        RB[sr] = *(const short8*)tmp;
    }
    float lng_[2], lnb_[2], gng_[2], gnb_[2];
#pragma unroll
    for (int jj = 0; jj < 2; ++jj) {
        lng_[jj] = ln1g[dv * 2 + jj];
        lnb_[jj] = ln1b[dv * 2 + jj];
        gng_[jj] = gng[dv * 2 + jj];
        gnb_[jj] = gnb[dv * 2 + jj];
    }
    float we0[2], we1[2], we2[2], be[2];
    if (EMBED) {
#pragma unroll
        for (int jj = 0; jj < 2; ++jj) {
            we0[jj] = w_in[0 * 128 + dv * 2 + jj];
            we1[jj] = w_in[1 * 128 + dv * 2 + jj];
            we2[jj] = w_in[2 * 128 + dv * 2 + jj];
            be[jj] = b_in[dv * 2 + jj];
        }
    }
    float cst[2], nst[2], mst[2];
#pragma unroll
    for (int jj = 0; jj < 2; ++jj) { cst[jj] = 0.f; nst[jj] = 0.f; mst[jj] = 0.f; }

    for (int i = tid; i < 16 * 136; i += 1024) ((ushort_t*)Hlds)[i] = 0;

    float cur0 = 0.f, cur1 = 0.f, cur2 = 0.f;
    float hin[2];
    if (EMBED) {
        const float* xp = x + (size_t)(b0 + bo) * TT * 3;
        cur0 = xp[0]; cur1 = xp[1]; cur2 = xp[2];
    } else {
        float2 v = *(const float2*)(h + ((size_t)(b0 + bo) * TT) * 128 + dv * 2);
        hin[0] = v.x; hin[1] = v.y;
    }
    lds_barrier();

    for (int t = 0; t < TT; ++t) {
        // ---- phase A: h_in + inline LN1 stats + Afrag stage + prefetch t+1 ----
        if (EMBED) {
#pragma unroll
            for (int jj = 0; jj < 2; ++jj)
                hin[jj] = cur0 * we0[jj] + cur1 * we1[jj] + cur2 * we2[jj] + be[jj];
        }
        float s = hin[0] + hin[1];
        float ss = hin[0] * hin[0] + hin[1] * hin[1];
#pragma unroll
        for (int off = 1; off < 64; off <<= 1) {
            s += __shfl_xor(s, off);
            ss += __shfl_xor(ss, off);
        }
        float mu = s * (1.f / 128.f);
        float rstd = rsqrtf(ss * (1.f / 128.f) - mu * mu + EPS);
        {
            ushort_t ab[2];
#pragma unroll
            for (int jj = 0; jj < 2; ++jj)
                ab[jj] = f2b((hin[jj] - mu) * rstd * lng_[jj] + lnb_[jj]);
            *(uint32_t*)&Afrag[bo][dv * 2] = *(const uint32_t*)ab;
        }
        float hin2[2] = {0.f, 0.f};
        float nx0 = 0.f, nx1 = 0.f, nx2 = 0.f;
        if (t + 1 < TT) {
            if (EMBED) {
                const float* xp = x + ((size_t)(b0 + bo) * TT + t + 1) * 3;
                nx0 = xp[0]; nx1 = xp[1]; nx2 = xp[2];
            } else {
                float2 v = *(const float2*)(h + ((size_t)(b0 + bo) * TT + t + 1) * 128 + dv * 2);
                hin2[0] = v.x; hin2[1] = v.y;
            }
        }
        lds_barrier();  // b1: Afrag + Hlds(prev C) visible; Xbuf(prev) consumed

        // ---- phase B: MFMA xg + r + bias (10 MFMAs/wave) ----
        short8 af[4], hf;
#pragma unroll
        for (int ks = 0; ks < 4; ++ks)
            af[ks] = *(const short8*)&Afrag[ml][ks * 32 + q * 8];
        hf = *(const short8*)&Hlds[ml][quarter * 32 + q * 8];
        floatx4 acc[2];
#pragma unroll
        for (int s = 0; s < 2; ++s) {
            float b = biasv[s];
            acc[s] = (floatx4){b, b, b, b};
        }
#pragma unroll
        for (int ks = 0; ks < 4; ++ks)
#pragma unroll
            for (int s = 0; s < 2; ++s)
                acc[s] = __builtin_amdgcn_mfma_f32_16x16x32_bf16(
                    af[ks], WB[ks][s], acc[s], 0, 0, 0);
#pragma unroll
        for (int sr = 0; sr < 2; ++sr)
            acc[sr] = __builtin_amdgcn_mfma_f32_16x16x32_bf16(
                hf, RB[sr], acc[sr], 0, 0, 0);
#pragma unroll
        for (int s = 0; s < 2; ++s)
#pragma unroll
            for (int r = 0; r < 4; ++r)
                Xbuf[q * 4 + r][gate * 128 + quarter * 32 + s * 16 + ml] = acc[s][r];
        lds_barrier();  // b2: Xbuf ready

        // ---- phase C: nonlinearities + GN + residual (2 dims/thread) ----
        float it[2], ft[2], zt[2], ot[2];
        {
            float2 a = *(const float2*)&Xbuf[bo][0 * 128 + dv * 2];
            it[0] = a.x; it[1] = a.y;
            float2 f = *(const float2*)&Xbuf[bo][1 * 128 + dv * 2];
            ft[0] = f.x; ft[1] = f.y;
            float2 z = *(const float2*)&Xbuf[bo][2 * 128 + dv * 2];
            zt[0] = z.x; zt[1] = z.y;
            float2 o = *(const float2*)&Xbuf[bo][3 * 128 + dv * 2];
            ot[0] = o.x; ot[1] = o.y;
        }
        float hv[2];
#pragma unroll
        for (int jj = 0; jj < 2; ++jj) {
            float mn = fmaxf(ft[jj] + mst[jj], it[jj]);
            float iv = __expf(it[jj] - mn);
            float fv = __expf(ft[jj] + mst[jj] - mn);
            float cn = fv * cst[jj] + iv * tanh_fast(zt[jj]);
            float nn = fv * nst[jj] + iv;
            hv[jj] = cn / (nn * (1.f + __expf(-ot[jj])));
            cst[jj] = cn; nst[jj] = nn; mst[jj] = mn;
        }
        // GroupNorm over head (32 dims): 2 local + shfl over dv bits 0-3 (16 lanes)
        float s2 = hv[0] + hv[1];
        float q2 = hv[0] * hv[0] + hv[1] * hv[1];
        s2 += __shfl_xor(s2, 1); q2 += __shfl_xor(q2, 1);
        s2 += __shfl_xor(s2, 2); q2 += __shfl_xor(q2, 2);
        s2 += __shfl_xor(s2, 4); q2 += __shfl_xor(q2, 4);
        s2 += __shfl_xor(s2, 8); q2 += __shfl_xor(q2, 8);
        float mu2 = s2 * (1.f / 32.f);
        float rstd2 = rsqrtf(q2 * (1.f / 32.f) - mu2 * mu2 + EPS);
        {
            if (!LASTONLY || t == TT - 1) {
                float o0 = hin[0] + (hv[0] - mu2) * rstd2 * gng_[0] + gnb_[0];
                float o1 = hin[1] + (hv[1] - mu2) * rstd2 * gng_[1] + gnb_[1];
                float* po = h + ((size_t)(b0 + bo) * TT + t) * 128 + dv * 2;
                *(float2*)po = make_float2(o0, o1);
            }
            ushort_t hb16[2];
            hb16[0] = f2b(hv[0]); hb16[1] = f2b(hv[1]);
            *(uint32_t*)&Hlds[bo][dv * 2] = *(const uint32_t*)hb16;
        }
        if (EMBED) { cur0 = nx0; cur1 = nx1; cur2 = nx2; }
        else { hin[0] = hin2[0]; hin[1] = hin2[1]; }
        // no barrier: next phase A writes only Afrag (disjoint); b1 orders
        // Hlds writes + Xbuf reads before next phase B.
    }
}

// ---------------- fused FFN: h += gelu(LN2(h) @ W1) @ W2, stats inline ----------------
// (unchanged from round 9 — proven) M=64 tiles, 3 wgs/CU. LAST: rows (b)*TT+TT-1.
template <bool LAST>
__global__ __launch_bounds__(256, 3) void k_ffn(
    float* __restrict__ h, const ushort_t* __restrict__ W1t,
    const ushort_t* __restrict__ W2t,
    const float* __restrict__ lng, const float* __restrict__ lnb) {
    __shared__ ushort_t As[64][136];
    __shared__ ushort_t T1[64][136];
    int tid = threadIdx.x;
    int lane = tid & 63, wave = tid >> 6;
    int q = lane >> 4, ml = lane & 15;
    int wn = wave * 32;
    size_t row0 = (size_t)blockIdx.x * 64;

    short8 W1B[2][4];
#pragma unroll
    for (int jn = 0; jn < 2; ++jn)
#pragma unroll
        for (int ks = 0; ks < 4; ++ks)
            W1B[jn][ks] = *(const short8*)(W1t +
                ((size_t)(wn + jn * 16 + ml) * 128 + ks * 32 + q * 8));

    int r = tid >> 2, qd = tid & 3;
    size_t grow = LAST ? ((row0 + r) * TT + (TT - 1)) : (row0 + r);
    const float* hrow = h + grow * 128 + qd * 32;
    float s = 0.f, ss = 0.f;
#pragma unroll
    for (int k = 0; k < 8; ++k) {
        float4 v = ((const float4*)hrow)[k];
        s += v.x + v.y + v.z + v.w;
        ss += v.x * v.x + v.y * v.y + v.z * v.z + v.w * v.w;
    }
    s += __shfl_xor(s, 1); ss += __shfl_xor(ss, 1);
    s += __shfl_xor(s, 2); ss += __shfl_xor(ss, 2);
    float mu = s * (1.f / 128.f);
    float rstd = rsqrtf(ss * (1.f / 128.f) - mu * mu + EPS);
#pragma unroll
    for (int kk = 0; kk < 4; ++kk) {
        float4 a = ((const float4*)hrow)[2 * kk];
        float4 b = ((const float4*)hrow)[2 * kk + 1];
        int c0 = qd * 32 + kk * 8;
        float4 g0 = *(const float4*)(lng + c0);
        float4 g1 = *(const float4*)(lng + c0 + 4);
        float4 b0 = *(const float4*)(lnb + c0);
        float4 b1 = *(const float4*)(lnb + c0 + 4);
        ushort_t p[8];
        p[0] = f2b((a.x - mu) * rstd * g0.x + b0.x);
        p[1] = f2b((a.y - mu) * rstd * g0.y + b0.y);
        p[2] = f2b((a.z - mu) * rstd * g0.z + b0.z);
        p[3] = f2b((a.w - mu) * rstd * g0.w + b0.w);
        p[4] = f2b((b.x - mu) * rstd * g1.x + b1.x);
        p[5] = f2b((b.y - mu) * rstd * g1.y + b1.y);
        p[6] = f2b((b.z - mu) * rstd * g1.z + b1.z);
        p[7] = f2b((b.w - mu) * rstd * g1.w + b1.w);
        *(short8*)&As[r][c0] = *(const short8*)p;
    }
    lds_barrier();

    floatx4 acc[4][2];
#pragma unroll
    for (int i = 0; i < 4; ++i)
#pragma unroll
        for (int j = 0; j < 2; ++j) acc[i][j] = (floatx4)0.f;
#pragma unroll
    for (int ks = 0; ks < 4; ++ks) {
        short8 af[4];
#pragma unroll
        for (int im = 0; im < 4; ++im)
            af[im] = *(const short8*)&As[im * 16 + ml][ks * 32 + q * 8];
#pragma unroll
        for (int im = 0; im < 4; ++im)
#pragma unroll
            for (int jn = 0; jn < 2; ++jn)
                acc[im][jn] = __builtin_amdgcn_mfma_f32_16x16x32_bf16(
                    af[im], W1B[jn][ks], acc[im][jn], 0, 0, 0);
    }
#pragma unroll
    for (int im = 0; im < 4; ++im)
#pragma unroll
        for (int jn = 0; jn < 2; ++jn)
#pragma unroll
            for (int rr = 0; rr < 4; ++rr) {
                float v = acc[im][jn][rr];
                float u = 0.7978845608028654f * (v + 0.044715f * v * v * v);
                float gv = 0.5f * v * (1.f + tanh_fast(u));
                T1[im * 16 + q * 4 + rr][wn + jn * 16 + ml] = f2b(gv);
            }
    short8 W2B[2][4];
#pragma unroll
    for (int jn = 0; jn < 2; ++jn)
#pragma unroll
        for (int ks = 0; ks < 4; ++ks)
            W2B[jn][ks] = *(const short8*)(W2t +
                ((size_t)(wn + jn * 16 + ml) * 128 + ks * 32 + q * 8));
    lds_barrier();

#pragma unroll
    for (int i = 0; i < 4; ++i)
#pragma unroll
        for (int j = 0; j < 2; ++j) acc[i][j] = (floatx4)0.f;
#pragma unroll
    for (int ks = 0; ks < 4; ++ks) {
        short8 af[4];
#pragma unroll
        for (int im = 0; im < 4; ++im)
            af[im] = *(const short8*)&T1[im * 16 + ml][ks * 32 + q * 8];
#pragma unroll
        for (int im = 0; im < 4; ++im)
#pragma unroll
            for (int jn = 0; jn < 2; ++jn)
                acc[im][jn] = __builtin_amdgcn_mfma_f32_16x16x32_bf16(
                    af[im], W2B[jn][ks], acc[im][jn], 0, 0, 0);
    }
#pragma unroll
    for (int im = 0; im < 4; ++im)
#pragma unroll
        for (int jn = 0; jn < 2; ++jn)
#pragma unroll
            for (int rr = 0; rr < 4; ++rr) {
                int rloc = im * 16 + q * 4 + rr;
                size_t rw = LAST ? ((row0 + rloc) * TT + (TT - 1)) : (row0 + rloc);
                int cc = wn + jn * 16 + ml;
                h[rw * 128 + cc] += acc[im][jn][rr];
            }
}

// ---------------- final LN (t=T-1 only) + matvec ----------------
__global__ __launch_bounds__(256) void k_out(const float* __restrict__ h,
                                             const float* __restrict__ lnfg,
                                             const float* __restrict__ lnfb,
                                             const float* __restrict__ w_out,
                                             const float* __restrict__ b_out,
                                             float* __restrict__ out) {
    int b = blockIdx.x * 4 + (threadIdx.x >> 6);
    int l = threadIdx.x & 63;
    const float* hr = h + ((size_t)b * TT + (TT - 1)) * 128;
    float2 v = *(const float2*)(hr + l * 2);
    float s = v.x + v.y, ss = v.x * v.x + v.y * v.y;
#pragma unroll
    for (int off = 1; off < 64; off <<= 1) {
        s += __shfl_xor(s, off);
        ss += __shfl_xor(ss, off);
    }
    float mu_ = s * (1.f / 128.f);
    float rstd = rsqrtf(ss * (1.f / 128.f) - mu_ * mu_ + EPS);
    float2 g = *(const float2*)(lnfg + l * 2);
    float2 bb = *(const float2*)(lnfb + l * 2);
    float2 w = *(const float2*)(w_out + l * 2);
    float dot = ((v.x - mu_) * rstd * g.x + bb.x) * w.x +
                ((v.y - mu_) * rstd * g.y + bb.y) * w.y;
#pragma unroll
    for (int off = 1; off < 64; off <<= 1) dot += __shfl_xor(dot, off);
    if (l == 0) out[b] = dot + b_out[0];
}

extern "C" void kernel_launch(void* const* d_in, const int* in_sizes, int n_in,
                              void* d_out, int out_size, void* d_ws, size_t ws_size,
                              hipStream_t stream) {
    const float* x    = (const float*)d_in[0];
    const float* w_in = (const float*)d_in[1];
    const float* b_in = (const float*)d_in[2];
    const float* ln1g = (const float*)d_in[3];
    const float* ln1b = (const float*)d_in[4];
    const float* Wg   = (const float*)d_in[5];
    const float* bg   = (const float*)d_in[6];
    const float* Rg   = (const float*)d_in[7];
    const float* gng  = (const float*)d_in[8];
    const float* gnb  = (const float*)d_in[9];
    const float* ln2g = (const float*)d_in[10];
    const float* ln2b = (const float*)d_in[11];
    const float* W1   = (const float*)d_in[12];
    const float* W2   = (const float*)d_in[13];
    const float* lnfg = (const float*)d_in[14];
    const float* lnfb = (const float*)d_in[15];
    const float* wout = (const float*)d_in[16];
    const float* bout = (const float*)d_in[17];
    float* out = (float*)d_out;

    // ws: h fp32 (134.2 MB) | Wgt bf16 [blk][512][128] | W1t | W2t
    float* h = (float*)d_ws;
    ushort_t* Wgt = (ushort_t*)(h + (size_t)MROWS * 128);
    ushort_t* W1t = Wgt + 2 * 512 * 128;
    ushort_t* W2t = W1t + 2 * 128 * 128;

    k_cvtall<<<(2 * 512 * 128 + 4 * 128 * 128) / 256, 256, 0, stream>>>(
        Wg, W1, W2, Wgt, W1t, W2t);

    // blk 0: embed fused into the scan (reads x, not h); full h written
    k_gslstm<true, false><<<BB / 16, 1024, 0, stream>>>(
        h, x, w_in, b_in, Wgt, bg, Rg, ln1g, ln1b, gng, gnb);
    k_ffn<false><<<MROWS / 64, 256, 0, stream>>>(h, W1t, W2t, ln2g, ln2b);
    // blk 1: h writes dead except t=T-1 (only FFN1@t=T-1 -> k_out read them)
    k_gslstm<false, true><<<BB / 16, 1024, 0, stream>>>(
        h, nullptr, nullptr, nullptr, Wgt + (size_t)512 * 128, bg + 512,
        Rg + (size_t)16384, ln1g + 128, ln1b + 128, gng + 128, gnb + 128);
    k_ffn<true><<<BB / 64, 256, 0, stream>>>(h, W1t + 16384, W2t + 16384,
                                             ln2g + 128, ln2b + 128);
    k_out<<<BB / 4, 256, 0, stream>>>(h, lnfg, lnfb, wout, bout, out);
}

// Round 11
// 438.277 us; speedup vs baseline: 1.0981x; 1.0981x over previous
//
#include <hip/hip_runtime.h>
#include <hip/hip_bf16.h>
#include <cstdint>
#include <cstddef>

#define EPS 1e-5f
#define BB 4096
#define TT 64
#define NBLK 2
#define MROWS (BB * TT)

typedef unsigned short ushort_t;
typedef __attribute__((ext_vector_type(8))) short short8;
typedef __attribute__((ext_vector_type(4))) float floatx4;

__device__ __forceinline__ ushort_t f2b(float f) {
    __hip_bfloat16 h = __float2bfloat16(f);
    return *reinterpret_cast<ushort_t*>(&h);
}
__device__ __forceinline__ float tanh_fast(float z) {
    return 1.f - 2.f / (__expf(2.f * z) + 1.f);
}
// LDS-only barrier, single asm statement (round-5 lesson: separate
// builtin_amdgcn_s_barrier is IntrNoMem and lets LDS ops hoist past the
// waitcnt). Omits vmcnt drain: global buffers are wg-exclusive.
__device__ __forceinline__ void lds_barrier() {
    asm volatile("s_waitcnt lgkmcnt(0)\n\ts_barrier" ::: "memory");
}

// ---------------- all weight converts in one launch ----------------
__global__ __launch_bounds__(256) void k_cvtall(
    const float* __restrict__ Wg, const float* __restrict__ W1,
    const float* __restrict__ W2, ushort_t* __restrict__ Wgt,
    ushort_t* __restrict__ W1t, ushort_t* __restrict__ W2t) {
    int idx = blockIdx.x * 256 + threadIdx.x;
    if (idx < 2 * 512 * 128) {
        int blk = idx >> 16, r = idx & 65535;
        int n = r >> 7, k = r & 127;
        Wgt[idx] = f2b(Wg[(size_t)blk * 65536 + k * 512 + n]);
    } else if (idx < 2 * 512 * 128 + 2 * 128 * 128) {
        int i2 = idx - 2 * 512 * 128;
        int blk = i2 >> 14, r = i2 & 16383;
        int n = r >> 7, k = r & 127;
        W1t[i2] = f2b(W1[(size_t)blk * 16384 + k * 128 + n]);
    } else {
        int i2 = idx - (2 * 512 * 128 + 2 * 128 * 128);
        int blk = i2 >> 14, r = i2 & 16383;
        int n = r >> 7, k = r & 127;
        W2t[i2] = f2b(W2[(size_t)blk * 16384 + k * 128 + n]);
    }
}

// ---------------- fused [embed +] gate-GEMM + sLSTM scan + GroupNorm + residual --------
// ROUND-9 PROVEN SHAPE (verbatim; best measured: 143 us, deterministic).
// grid = BB/16 = 256 wgs (1 wg/CU), 512 thr = 8 waves = 2 waves/SIMD.
// Wave = (gate, half). 16-wave reshard (r10) regressed: barrier skew; multi-wg
// scans (r5/r8) raced. This shape is the scan's local optimum.
template <bool EMBED, bool LASTONLY>
__global__ __launch_bounds__(512, 2) void k_gslstm(
    float* __restrict__ h, const float* __restrict__ x,
    const float* __restrict__ w_in, const float* __restrict__ b_in,
    const ushort_t* __restrict__ Wgt, const float* __restrict__ bg,
    const float* __restrict__ Rg,
    const float* __restrict__ ln1g, const float* __restrict__ ln1b,
    const float* __restrict__ gng, const float* __restrict__ gnb) {
    __shared__ ushort_t Afrag[16][136];  // LN1(h_in) bf16, [m][k]
    __shared__ ushort_t Hlds[16][136];   // h_prev bf16, [m][k]
    __shared__ float Xbuf[16][516];      // gate preacts fp32, [b][g*128+d]

    int tid = threadIdx.x;        // 0..511
    int lane = tid & 63;
    int wave = tid >> 6;          // 0..7
    int gate = wave >> 1;
    int half = wave & 1;
    int q = lane >> 4, ml = lane & 15;
    int bo = tid >> 5;            // local batch 0..15 (phase A/C ownership)
    int dl = tid & 31;            // dims dl*4 .. dl*4+3
    int b0 = blockIdx.x * 16;

    // ---- static setup ----
    short8 WB[4][4];  // [k-slice][n-slice] of this wave's 64 columns
#pragma unroll
    for (int ks = 0; ks < 4; ++ks)
#pragma unroll
        for (int s = 0; s < 4; ++s)
            WB[ks][s] = *(const short8*)(Wgt +
                ((size_t)(gate * 128 + half * 64 + s * 16 + ml) * 128 + ks * 32 + q * 8));
    float biasv[4];
#pragma unroll
    for (int s = 0; s < 4; ++s) biasv[s] = bg[gate * 128 + half * 64 + s * 16 + ml];
    short8 RB[2][2];
#pragma unroll
    for (int hb = 0; hb < 2; ++hb)
#pragma unroll
        for (int sr = 0; sr < 2; ++sr) {
            ushort_t tmp[8];
#pragma unroll
            for (int jj = 0; jj < 8; ++jj)
                tmp[jj] = f2b(Rg[((size_t)(gate * 4 + 2 * half + hb) * 32 + q * 8 + jj) * 32 +
                               sr * 16 + ml]);
            RB[hb][sr] = *(const short8*)tmp;
        }
    float lng_[4], lnb_[4], gng_[4], gnb_[4];
#pragma unroll
    for (int jj = 0; jj < 4; ++jj) {
        lng_[jj] = ln1g[dl * 4 + jj];
        lnb_[jj] = ln1b[dl * 4 + jj];
        gng_[jj] = gng[dl * 4 + jj];
        gnb_[jj] = gnb[dl * 4 + jj];
    }
    float we0[4], we1[4], we2[4], be[4];
    if (EMBED) {
#pragma unroll
        for (int jj = 0; jj < 4; ++jj) {
            we0[jj] = w_in[0 * 128 + dl * 4 + jj];
            we1[jj] = w_in[1 * 128 + dl * 4 + jj];
            we2[jj] = w_in[2 * 128 + dl * 4 + jj];
            be[jj] = b_in[dl * 4 + jj];
        }
    }
    float cst[4], nst[4], mst[4];
#pragma unroll
    for (int jj = 0; jj < 4; ++jj) { cst[jj] = 0.f; nst[jj] = 0.f; mst[jj] = 0.f; }

    for (int i = tid; i < 16 * 136; i += 512) ((ushort_t*)Hlds)[i] = 0;

    float cur0 = 0.f, cur1 = 0.f, cur2 = 0.f;
    float hin[4];
    if (EMBED) {
        const float* xp = x + (size_t)(b0 + bo) * TT * 3;
        cur0 = xp[0]; cur1 = xp[1]; cur2 = xp[2];
    } else {
        float4 v = *(const float4*)(h + ((size_t)(b0 + bo) * TT) * 128 + dl * 4);
        hin[0] = v.x; hin[1] = v.y; hin[2] = v.z; hin[3] = v.w;
    }
    lds_barrier();

    for (int t = 0; t < TT; ++t) {
        // ---- phase A: h_in + inline LN1 stats + Afrag stage + prefetch t+1 ----
        if (EMBED) {
#pragma unroll
            for (int jj = 0; jj < 4; ++jj)
                hin[jj] = cur0 * we0[jj] + cur1 * we1[jj] + cur2 * we2[jj] + be[jj];
        }
        float s = 0.f, ss = 0.f;
#pragma unroll
        for (int jj = 0; jj < 4; ++jj) { s += hin[jj]; ss += hin[jj] * hin[jj]; }
#pragma unroll
        for (int off = 1; off < 32; off <<= 1) {
            s += __shfl_xor(s, off);
            ss += __shfl_xor(ss, off);
        }
        float mu = s * (1.f / 128.f);
        float rstd = rsqrtf(ss * (1.f / 128.f) - mu * mu + EPS);
        {
            ushort_t ab[4];
#pragma unroll
            for (int jj = 0; jj < 4; ++jj)
                ab[jj] = f2b((hin[jj] - mu) * rstd * lng_[jj] + lnb_[jj]);
            *(uint2*)&Afrag[bo][dl * 4] = *(const uint2*)ab;
        }
        float hin2[4] = {0.f, 0.f, 0.f, 0.f};
        float nx0 = 0.f, nx1 = 0.f, nx2 = 0.f;
        if (t + 1 < TT) {
            if (EMBED) {
                const float* xp = x + ((size_t)(b0 + bo) * TT + t + 1) * 3;
                nx0 = xp[0]; nx1 = xp[1]; nx2 = xp[2];
            } else {
                float4 v = *(const float4*)(h + ((size_t)(b0 + bo) * TT + t + 1) * 128 + dl * 4);
                hin2[0] = v.x; hin2[1] = v.y; hin2[2] = v.z; hin2[3] = v.w;
            }
        }
        lds_barrier();  // b1: Afrag + Hlds(prev C) visible; Xbuf(prev) consumed

        // ---- phase B: MFMA xg + r + bias ----
        short8 af[4], hf[2];
#pragma unroll
        for (int ks = 0; ks < 4; ++ks)
            af[ks] = *(const short8*)&Afrag[ml][ks * 32 + q * 8];
#pragma unroll
        for (int hb = 0; hb < 2; ++hb)
            hf[hb] = *(const short8*)&Hlds[ml][(2 * half + hb) * 32 + q * 8];
        floatx4 acc[4];
#pragma unroll
        for (int s4 = 0; s4 < 4; ++s4) {
            float b = biasv[s4];
            acc[s4] = (floatx4){b, b, b, b};
        }
#pragma unroll
        for (int ks = 0; ks < 4; ++ks)
#pragma unroll
            for (int s4 = 0; s4 < 4; ++s4)
                acc[s4] = __builtin_amdgcn_mfma_f32_16x16x32_bf16(
                    af[ks], WB[ks][s4], acc[s4], 0, 0, 0);
#pragma unroll
        for (int hb = 0; hb < 2; ++hb)
#pragma unroll
            for (int sr = 0; sr < 2; ++sr)
                acc[hb * 2 + sr] = __builtin_amdgcn_mfma_f32_16x16x32_bf16(
                    hf[hb], RB[hb][sr], acc[hb * 2 + sr], 0, 0, 0);
#pragma unroll
        for (int s4 = 0; s4 < 4; ++s4)
#pragma unroll
            for (int r = 0; r < 4; ++r)
                Xbuf[q * 4 + r][gate * 128 + half * 64 + s4 * 16 + ml] = acc[s4][r];
        lds_barrier();  // b2: Xbuf ready

        // ---- phase C: nonlinearities + GN + residual (4 dims/thread) ----
        float it[4], ft[4], zt[4], ot[4];
        {
            float4 a = *(const float4*)&Xbuf[bo][0 * 128 + dl * 4];
            it[0] = a.x; it[1] = a.y; it[2] = a.z; it[3] = a.w;
            float4 f = *(const float4*)&Xbuf[bo][1 * 128 + dl * 4];
            ft[0] = f.x; ft[1] = f.y; ft[2] = f.z; ft[3] = f.w;
            float4 z = *(const float4*)&Xbuf[bo][2 * 128 + dl * 4];
            zt[0] = z.x; zt[1] = z.y; zt[2] = z.z; zt[3] = z.w;
            float4 o = *(const float4*)&Xbuf[bo][3 * 128 + dl * 4];
            ot[0] = o.x; ot[1] = o.y; ot[2] = o.z; ot[3] = o.w;
        }
        float hv[4];
#pragma unroll
        for (int jj = 0; jj < 4; ++jj) {
            float mn = fmaxf(ft[jj] + mst[jj], it[jj]);
            float iv = __expf(it[jj] - mn);
            float fv = __expf(ft[jj] + mst[jj] - mn);
            float cn = fv * cst[jj] + iv * tanh_fast(zt[jj]);
            float nn = fv * nst[jj] + iv;
            hv[jj] = cn / (nn * (1.f + __expf(-ot[jj])));
            cst[jj] = cn; nst[jj] = nn; mst[jj] = mn;
        }
        // GroupNorm over head (32 dims): 4 local + shfl over dl bits 0-2
        float s2 = 0.f, q2 = 0.f;
#pragma unroll
        for (int jj = 0; jj < 4; ++jj) { s2 += hv[jj]; q2 += hv[jj] * hv[jj]; }
        s2 += __shfl_xor(s2, 1); q2 += __shfl_xor(q2, 1);
        s2 += __shfl_xor(s2, 2); q2 += __shfl_xor(q2, 2);
        s2 += __shfl_xor(s2, 4); q2 += __shfl_xor(q2, 4);
        float mu2 = s2 * (1.f / 32.f);
        float rstd2 = rsqrtf(q2 * (1.f / 32.f) - mu2 * mu2 + EPS);
        {
            if (!LASTONLY || t == TT - 1) {
                float o[4];
#pragma unroll
                for (int jj = 0; jj < 4; ++jj)
                    o[jj] = hin[jj] + (hv[jj] - mu2) * rstd2 * gng_[jj] + gnb_[jj];
                float* po = h + ((size_t)(b0 + bo) * TT + t) * 128 + dl * 4;
                *(float4*)po = make_float4(o[0], o[1], o[2], o[3]);
            }
            ushort_t hb16[4];
#pragma unroll
            for (int jj = 0; jj < 4; ++jj) hb16[jj] = f2b(hv[jj]);
            *(uint2*)&Hlds[bo][dl * 4] = *(const uint2*)hb16;
        }
        if (EMBED) { cur0 = nx0; cur1 = nx1; cur2 = nx2; }
        else {
#pragma unroll
            for (int jj = 0; jj < 4; ++jj) hin[jj] = hin2[jj];
        }
        // no barrier: next phase A writes only Afrag (disjoint); b1 orders
        // Hlds writes + Xbuf reads before next phase B.
    }
}

// ---------------- fused FFN: h += gelu(LN2(h) @ W1) @ W2, stats inline ----------------
// M=32 tiles, 17.4 KB LDS, __launch_bounds__(256,6) -> 6 wgs/CU (was 3 at M=64):
// doubles co-resident wgs so barrier/memory stalls overlap. Per wave: 32-col
// slice, 2 row-tiles, 16 MFMAs per GEMM. LAST: rows map to (batch)*TT + TT-1.
template <bool LAST>
__global__ __launch_bounds__(256, 6) void k_ffn(
    float* __restrict__ h, const ushort_t* __restrict__ W1t,
    const ushort_t* __restrict__ W2t,
    const float* __restrict__ lng, const float* __restrict__ lnb) {
    __shared__ ushort_t As[32][136];
    __shared__ ushort_t T1[32][136];
    int tid = threadIdx.x;
    int lane = tid & 63, wave = tid >> 6;
    int q = lane >> 4, ml = lane & 15;
    int wn = wave * 32;  // wave's 32-column slice
    size_t row0 = (size_t)blockIdx.x * 32;

    // hoist W1 fragments (latency hidden under stats)
    short8 W1B[2][4];
#pragma unroll
    for (int jn = 0; jn < 2; ++jn)
#pragma unroll
        for (int ks = 0; ks < 4; ++ks)
            W1B[jn][ks] = *(const short8*)(W1t +
                ((size_t)(wn + jn * 16 + ml) * 128 + ks * 32 + q * 8));

    // inline LN2 stats: 8 threads per row, 16 dims each
    int r = tid >> 3, qd = tid & 7;
    size_t grow = LAST ? ((row0 + r) * TT + (TT - 1)) : (row0 + r);
    const float* hrow = h + grow * 128 + qd * 16;
    float s = 0.f, ss = 0.f;
#pragma unroll
    for (int k = 0; k < 4; ++k) {
        float4 v = ((const float4*)hrow)[k];
        s += v.x + v.y + v.z + v.w;
        ss += v.x * v.x + v.y * v.y + v.z * v.z + v.w * v.w;
    }
    s += __shfl_xor(s, 1); ss += __shfl_xor(ss, 1);
    s += __shfl_xor(s, 2); ss += __shfl_xor(ss, 2);
    s += __shfl_xor(s, 4); ss += __shfl_xor(ss, 4);
    float mu = s * (1.f / 128.f);
    float rstd = rsqrtf(ss * (1.f / 128.f) - mu * mu + EPS);
#pragma unroll
    for (int kk = 0; kk < 2; ++kk) {
        float4 a = ((const float4*)hrow)[2 * kk];
        float4 b = ((const float4*)hrow)[2 * kk + 1];
        int c0 = qd * 16 + kk * 8;
        float4 g0 = *(const float4*)(lng + c0);
        float4 g1 = *(const float4*)(lng + c0 + 4);
        float4 b0 = *(const float4*)(lnb + c0);
        float4 b1 = *(const float4*)(lnb + c0 + 4);
        ushort_t p[8];
        p[0] = f2b((a.x - mu) * rstd * g0.x + b0.x);
        p[1] = f2b((a.y - mu) * rstd * g0.y + b0.y);
        p[2] = f2b((a.z - mu) * rstd * g0.z + b0.z);
        p[3] = f2b((a.w - mu) * rstd * g0.w + b0.w);
        p[4] = f2b((b.x - mu) * rstd * g1.x + b1.x);
        p[5] = f2b((b.y - mu) * rstd * g1.y + b1.y);
        p[6] = f2b((b.z - mu) * rstd * g1.z + b1.z);
        p[7] = f2b((b.w - mu) * rstd * g1.w + b1.w);
        *(short8*)&As[r][c0] = *(const short8*)p;
    }
    lds_barrier();

    // MFMA1: t1 = gelu(As @ W1), 2 row-tiles x 2 col-slices
    floatx4 acc[2][2];
#pragma unroll
    for (int i = 0; i < 2; ++i)
#pragma unroll
        for (int j = 0; j < 2; ++j) acc[i][j] = (floatx4)0.f;
#pragma unroll
    for (int ks = 0; ks < 4; ++ks) {
        short8 af[2];
#pragma unroll
        for (int im = 0; im < 2; ++im)
            af[im] = *(const short8*)&As[im * 16 + ml][ks * 32 + q * 8];
#pragma unroll
        for (int im = 0; im < 2; ++im)
#pragma unroll
            for (int jn = 0; jn < 2; ++jn)
                acc[im][jn] = __builtin_amdgcn_mfma_f32_16x16x32_bf16(
                    af[im], W1B[jn][ks], acc[im][jn], 0, 0, 0);
    }
#pragma unroll
    for (int im = 0; im < 2; ++im)
#pragma unroll
        for (int jn = 0; jn < 2; ++jn)
#pragma unroll
            for (int rr = 0; rr < 4; ++rr) {
                float v = acc[im][jn][rr];
                float u = 0.7978845608028654f * (v + 0.044715f * v * v * v);
                float gv = 0.5f * v * (1.f + tanh_fast(u));
                T1[im * 16 + q * 4 + rr][wn + jn * 16 + ml] = f2b(gv);
            }
    // prefetch W2 fragments before the barrier
    short8 W2B[2][4];
#pragma unroll
    for (int jn = 0; jn < 2; ++jn)
#pragma unroll
        for (int ks = 0; ks < 4; ++ks)
            W2B[jn][ks] = *(const short8*)(W2t +
                ((size_t)(wn + jn * 16 + ml) * 128 + ks * 32 + q * 8));
    lds_barrier();

    // MFMA2: h += T1 @ W2
#pragma unroll
    for (int i = 0; i < 2; ++i)
#pragma unroll
        for (int j = 0; j < 2; ++j) acc[i][j] = (floatx4)0.f;
#pragma unroll
    for (int ks = 0; ks < 4; ++ks) {
        short8 af[2];
#pragma unroll
        for (int im = 0; im < 2; ++im)
            af[im] = *(const short8*)&T1[im * 16 + ml][ks * 32 + q * 8];
#pragma unroll
        for (int im = 0; im < 2; ++im)
#pragma unroll
            for (int jn = 0; jn < 2; ++jn)
                acc[im][jn] = __builtin_amdgcn_mfma_f32_16x16x32_bf16(
                    af[im], W2B[jn][ks], acc[im][jn], 0, 0, 0);
    }
#pragma unroll
    for (int im = 0; im < 2; ++im)
#pragma unroll
        for (int jn = 0; jn < 2; ++jn)
#pragma unroll
            for (int rr = 0; rr < 4; ++rr) {
                int rloc = im * 16 + q * 4 + rr;
                size_t rw = LAST ? ((row0 + rloc) * TT + (TT - 1)) : (row0 + rloc);
                int cc = wn + jn * 16 + ml;
                h[rw * 128 + cc] += acc[im][jn][rr];
            }
}

// ---------------- final LN (t=T-1 only) + matvec ----------------
__global__ __launch_bounds__(256) void k_out(const float* __restrict__ h,
                                             const float* __restrict__ lnfg,
                                             const float* __restrict__ lnfb,
                                             const float* __restrict__ w_out,
                                             const float* __restrict__ b_out,
                                             float* __restrict__ out) {
    int b = blockIdx.x * 4 + (threadIdx.x >> 6);
    int l = threadIdx.x & 63;
    const float* hr = h + ((size_t)b * TT + (TT - 1)) * 128;
    float2 v = *(const float2*)(hr + l * 2);
    float s = v.x + v.y, ss = v.x * v.x + v.y * v.y;
#pragma unroll
    for (int off = 1; off < 64; off <<= 1) {
        s += __shfl_xor(s, off);
        ss += __shfl_xor(ss, off);
    }
    float mu_ = s * (1.f / 128.f);
    float rstd = rsqrtf(ss * (1.f / 128.f) - mu_ * mu_ + EPS);
    float2 g = *(const float2*)(lnfg + l * 2);
    float2 bb = *(const float2*)(lnfb + l * 2);
    float2 w = *(const float2*)(w_out + l * 2);
    float dot = ((v.x - mu_) * rstd * g.x + bb.x) * w.x +
                ((v.y - mu_) * rstd * g.y + bb.y) * w.y;
#pragma unroll
    for (int off = 1; off < 64; off <<= 1) dot += __shfl_xor(dot, off);
    if (l == 0) out[b] = dot + b_out[0];
}

extern "C" void kernel_launch(void* const* d_in, const int* in_sizes, int n_in,
                              void* d_out, int out_size, void* d_ws, size_t ws_size,
                              hipStream_t stream) {
    const float* x    = (const float*)d_in[0];
    const float* w_in = (const float*)d_in[1];
    const float* b_in = (const float*)d_in[2];
    const float* ln1g = (const float*)d_in[3];
    const float* ln1b = (const float*)d_in[4];
    const float* Wg   = (const float*)d_in[5];
    const float* bg   = (const float*)d_in[6];
    const float* Rg   = (const float*)d_in[7];
    const float* gng  = (const float*)d_in[8];
    const float* gnb  = (const float*)d_in[9];
    const float* ln2g = (const float*)d_in[10];
    const float* ln2b = (const float*)d_in[11];
    const float* W1   = (const float*)d_in[12];
    const float* W2   = (const float*)d_in[13];
    const float* lnfg = (const float*)d_in[14];
    const float* lnfb = (const float*)d_in[15];
    const float* wout = (const float*)d_in[16];
    const float* bout = (const float*)d_in[17];
    float* out = (float*)d_out;

    // ws: h fp32 (134.2 MB) | Wgt bf16 [blk][512][128] | W1t | W2t
    float* h = (float*)d_ws;
    ushort_t* Wgt = (ushort_t*)(h + (size_t)MROWS * 128);
    ushort_t* W1t = Wgt + 2 * 512 * 128;
    ushort_t* W2t = W1t + 2 * 128 * 128;

    k_cvtall<<<(2 * 512 * 128 + 4 * 128 * 128) / 256, 256, 0, stream>>>(
        Wg, W1, W2, Wgt, W1t, W2t);

    // blk 0: embed fused into the scan (reads x, not h); full h written
    k_gslstm<true, false><<<BB / 16, 512, 0, stream>>>(
        h, x, w_in, b_in, Wgt, bg, Rg, ln1g, ln1b, gng, gnb);
    k_ffn<false><<<MROWS / 32, 256, 0, stream>>>(h, W1t, W2t, ln2g, ln2b);
    // blk 1: h writes dead except t=T-1 (only FFN1@t=T-1 -> k_out read them)
    k_gslstm<false, true><<<BB / 16, 512, 0, stream>>>(
        h, nullptr, nullptr, nullptr, Wgt + (size_t)512 * 128, bg + 512,
        Rg + (size_t)16384, ln1g + 128, ln1b + 128, gng + 128, gnb + 128);
    k_ffn<true><<<BB / 32, 256, 0, stream>>>(h, W1t + 16384, W2t + 16384,
                                             ln2g + 128, ln2b + 128);
    k_out<<<BB / 4, 256, 0, stream>>>(h, lnfg, lnfb, wout, bout, out);
}